// Round 2
// baseline (791.659 us; speedup 1.0000x reference)
//
#include <hip/hip_runtime.h>

// FrozenHopfield: obs-mean -> random projection -> cosine-sim attention over
// vocab embeddings -> softmax(beta*sims) @ word_embs.
//
// B=256, C=3, HW=7056, HID=768, VOCAB=50257. Two big GEMMs (19.8 GF each)
// done in bf16 MFMA 16x16x32 with fp32 accumulate. Logits bounded in [-8,8]
// so softmax needs no max subtraction: E=exp(logit), state=(E@W)/rowsum(E).
//
// R1 fix: k_gemm1/k_gemm2 staged only HALF the 128x32 LDS tile (256 thr x 8
// elems = 2048 of 4096). Rows 64..127 were stale garbage -> NaN/garbage out.
// Each thread now loads rows ar and ar+64.

#define VOCAB 50257
#define VPAD  50304   // 393*128
#define HID   768
#define BATCH 256
#define IN    7056
#define INPAD 7072    // 221*32
#define SPLITS 32
#define CHUNK 1600    // k-elems per split (1600*32 = 51200 >= VPAD)

typedef __attribute__((ext_vector_type(8))) __bf16 bf16x8;
typedef __attribute__((ext_vector_type(4))) float f32x4;

__device__ inline unsigned short f2bf(float f) {
  union { float f; unsigned u; } v; v.f = f;
  unsigned r = v.u + 0x7fffu + ((v.u >> 16) & 1u);   // RNE
  return (unsigned short)(r >> 16);
}

// ---------------- prep kernels ----------------

// Wb[v][h] = bf16(W[v][h]) (zero pad rows), inv_en[v] = 1/||W_v|| (0 for pads)
__global__ __launch_bounds__(256) void k_wb(const float* __restrict__ W,
                                            unsigned short* __restrict__ Wb,
                                            float* __restrict__ inv_en) {
  int v = blockIdx.x, t = threadIdx.x;
  float ss = 0.f;
  if (v < VOCAB) {
    for (int i = 0; i < 3; i++) {
      float x = W[(size_t)v * HID + t + i * 256];
      Wb[(size_t)v * HID + t + i * 256] = f2bf(x);
      ss += x * x;
    }
  } else {
    for (int i = 0; i < 3; i++) Wb[(size_t)v * HID + t + i * 256] = 0;
  }
  for (int m = 1; m < 64; m <<= 1) ss += __shfl_xor(ss, m, 64);
  __shared__ float sacc[4];
  if ((t & 63) == 0) sacc[t >> 6] = ss;
  __syncthreads();
  if (t == 0) {
    float tot = sacc[0] + sacc[1] + sacc[2] + sacc[3];
    inv_en[v] = (v < VOCAB) ? (1.f / sqrtf(tot)) : 0.f;
  }
}

// WbT[h][v] = bf16(W[v][h]) via 64x64 LDS tile transpose
__global__ __launch_bounds__(256) void k_wbt(const float* __restrict__ W,
                                             unsigned short* __restrict__ WbT) {
  __shared__ float Ts[64][65];
  int v0 = blockIdx.x * 64, h0 = blockIdx.y * 64;
  int tx = threadIdx.x, ty = threadIdx.y;   // (64,4)
  for (int i = 0; i < 16; i++) {
    int r = i * 4 + ty;
    int v = v0 + r;
    Ts[r][tx] = (v < VOCAB) ? W[(size_t)v * HID + h0 + tx] : 0.f;
  }
  __syncthreads();
  for (int i = 0; i < 16; i++) {
    int r = i * 4 + ty;                      // h-local
    WbT[(size_t)(h0 + r) * VPAD + v0 + tx] = f2bf(Ts[tx][r]);
  }
}

// obsb[b][i] = bf16(mean_c obs[b][c][i]), zero pad cols
__global__ __launch_bounds__(256) void k_obs(const float* __restrict__ obs,
                                             unsigned short* __restrict__ obsb) {
  int b = blockIdx.x, t = threadIdx.x;
  const size_t base = (size_t)b * 3 * IN;
  for (int c = t; c < INPAD; c += 256) {
    float m = 0.f;
    if (c < IN)
      m = (obs[base + c] + obs[base + IN + c] + obs[base + 2 * IN + c]) * (1.f / 3.f);
    obsb[b * INPAD + c] = f2bf(m);
  }
}

__global__ __launch_bounds__(256) void k_proj(const float* __restrict__ proj,
                                              unsigned short* __restrict__ projb) {
  int h = blockIdx.x, t = threadIdx.x;
  for (int c = t; c < INPAD; c += 256) {
    float x = (c < IN) ? proj[(size_t)h * IN + c] : 0.f;
    projb[h * INPAD + c] = f2bf(x);
  }
}

// ---------------- q projection GEMM: q = obs @ proj^T  (64x64 tile, BK=32) ----

__global__ __launch_bounds__(256) void k_qgemm(const unsigned short* __restrict__ A,  // obsb [256][INPAD]
                                               const unsigned short* __restrict__ Bm, // projb [768][INPAD]
                                               float* __restrict__ q) {
  __shared__ unsigned short As[64][32];
  __shared__ unsigned short Bs[64][32];
  const int t = threadIdx.x;
  const int lane = t & 63, wave = t >> 6;
  const int wm = wave >> 1, wn = wave & 1;
  const int quad = lane >> 4, lo = lane & 15;
  const int m0 = blockIdx.y * 64, n0 = blockIdx.x * 64;
  const int ar = t >> 2, ac = (t & 3) * 8;
  f32x4 acc[2][2];
  for (int i = 0; i < 2; i++)
    for (int j = 0; j < 2; j++) acc[i][j] = (f32x4){0.f, 0.f, 0.f, 0.f};
  const unsigned short* aptr = &A[(m0 + ar) * INPAD + ac];
  const unsigned short* bptr = &Bm[(n0 + ar) * INPAD + ac];
  for (int k0 = 0; k0 < INPAD; k0 += 32) {
    uint4 av = *(const uint4*)(aptr + k0);
    uint4 bv = *(const uint4*)(bptr + k0);
    __syncthreads();
    *(uint4*)&As[ar][ac] = av;
    *(uint4*)&Bs[ar][ac] = bv;
    __syncthreads();
    bf16x8 af[2], bfr[2];
    for (int i = 0; i < 2; i++) {
      af[i]  = *(const bf16x8*)&As[wm * 32 + i * 16 + lo][quad * 8];
      bfr[i] = *(const bf16x8*)&Bs[wn * 32 + i * 16 + lo][quad * 8];
    }
    for (int mi = 0; mi < 2; mi++)
      for (int ni = 0; ni < 2; ni++)
        acc[mi][ni] = __builtin_amdgcn_mfma_f32_16x16x32_bf16(af[mi], bfr[ni], acc[mi][ni], 0, 0, 0);
  }
  for (int mi = 0; mi < 2; mi++)
    for (int ni = 0; ni < 2; ni++)
      for (int r = 0; r < 4; r++) {
        int row = m0 + wm * 32 + mi * 16 + quad * 4 + r;   // b
        int col = n0 + wn * 32 + ni * 16 + lo;             // h
        q[row * HID + col] = acc[mi][ni][r];
      }
}

// qhat[b][h] = bf16(q * beta/||q_b||); also zero the rowsum accumulator l
__global__ __launch_bounds__(256) void k_qhat(const float* __restrict__ q,
                                              const int* __restrict__ beta,
                                              unsigned short* __restrict__ qhat,
                                              float* __restrict__ l) {
  int b = blockIdx.x, t = threadIdx.x;
  float v0 = q[b * HID + t], v1 = q[b * HID + t + 256], v2 = q[b * HID + t + 512];
  float ss = v0 * v0 + v1 * v1 + v2 * v2;
  for (int m = 1; m < 64; m <<= 1) ss += __shfl_xor(ss, m, 64);
  __shared__ float sacc[4];
  if ((t & 63) == 0) sacc[t >> 6] = ss;
  __syncthreads();
  float tot = sacc[0] + sacc[1] + sacc[2] + sacc[3];
  // ref denom is (qn*en + 1e-8); qn*en ~ 1.3e3 so eps is rel ~7e-12: folded out.
  float scale = (float)beta[0] / sqrtf(tot);
  qhat[b * HID + t]       = f2bf(v0 * scale);
  qhat[b * HID + t + 256] = f2bf(v1 * scale);
  qhat[b * HID + t + 512] = f2bf(v2 * scale);
  if (t == 0) l[b] = 0.f;
}

// ---------------- GEMM1: E = exp((qhat @ Wb^T) * inv_en), rowsums into l ----

__global__ __launch_bounds__(256) void k_gemm1(const unsigned short* __restrict__ A,   // qhat [256][768]
                                               const unsigned short* __restrict__ Bm,  // Wb [VPAD][768]
                                               const float* __restrict__ inv_en,
                                               unsigned short* __restrict__ E,         // [256][VPAD]
                                               float* __restrict__ l) {
  __shared__ unsigned short As[128][32];
  __shared__ unsigned short Bs[128][32];
  __shared__ float rowsum[128];
  const int t = threadIdx.x;
  const int lane = t & 63, wave = t >> 6;
  const int wm = wave >> 1, wn = wave & 1;
  const int quad = lane >> 4, lo = lane & 15;
  const int m0 = blockIdx.y * 128, n0 = blockIdx.x * 128;
  const int ar = t >> 2, ac = (t & 3) * 8;
  if (t < 128) rowsum[t] = 0.f;
  f32x4 acc[4][4];
  for (int i = 0; i < 4; i++)
    for (int j = 0; j < 4; j++) acc[i][j] = (f32x4){0.f, 0.f, 0.f, 0.f};
  const unsigned short* aptr  = &A[(m0 + ar) * HID + ac];
  const unsigned short* aptr2 = &A[(m0 + ar + 64) * HID + ac];
  const unsigned short* bptr  = &Bm[(size_t)(n0 + ar) * HID + ac];
  const unsigned short* bptr2 = &Bm[(size_t)(n0 + ar + 64) * HID + ac];
  for (int k0 = 0; k0 < HID; k0 += 32) {
    uint4 av0 = *(const uint4*)(aptr + k0);
    uint4 av1 = *(const uint4*)(aptr2 + k0);
    uint4 bv0 = *(const uint4*)(bptr + k0);
    uint4 bv1 = *(const uint4*)(bptr2 + k0);
    __syncthreads();
    *(uint4*)&As[ar][ac]      = av0;
    *(uint4*)&As[ar + 64][ac] = av1;
    *(uint4*)&Bs[ar][ac]      = bv0;
    *(uint4*)&Bs[ar + 64][ac] = bv1;
    __syncthreads();
    bf16x8 af[4], bfr[4];
    for (int i = 0; i < 4; i++) {
      af[i]  = *(const bf16x8*)&As[wm * 64 + i * 16 + lo][quad * 8];
      bfr[i] = *(const bf16x8*)&Bs[wn * 64 + i * 16 + lo][quad * 8];
    }
    for (int mi = 0; mi < 4; mi++)
      for (int ni = 0; ni < 4; ni++)
        acc[mi][ni] = __builtin_amdgcn_mfma_f32_16x16x32_bf16(af[mi], bfr[ni], acc[mi][ni], 0, 0, 0);
  }
  // epilogue: E = exp(acc * inv_en) (masked past VOCAB), rowsum reduce
  for (int mi = 0; mi < 4; mi++)
    for (int ni = 0; ni < 4; ni++) {
      int vg = n0 + wn * 64 + ni * 16 + lo;
      float ie = inv_en[vg];
      bool valid = (vg < VOCAB);
      for (int r = 0; r < 4; r++) {
        int row = wm * 64 + mi * 16 + quad * 4 + r;
        float e = valid ? __expf(acc[mi][ni][r] * ie) : 0.f;   // logits in [-8,8]
        E[(size_t)(m0 + row) * VPAD + vg] = f2bf(e);
        float s = e;
        s += __shfl_xor(s, 1, 64);
        s += __shfl_xor(s, 2, 64);
        s += __shfl_xor(s, 4, 64);
        s += __shfl_xor(s, 8, 64);
        if (lo == 0) atomicAdd(&rowsum[row], s);
      }
    }
  __syncthreads();
  if (t < 128) atomicAdd(&l[m0 + t], rowsum[t]);
}

// ---------------- GEMM2 (K-split): Pp[s][h][b] = partial sum_v WbT[h][v]*E[b][v] ----

__global__ __launch_bounds__(256) void k_gemm2(const unsigned short* __restrict__ A,   // WbT [768][VPAD]
                                               const unsigned short* __restrict__ Bm,  // E [256][VPAD]
                                               float* __restrict__ Pp) {
  __shared__ unsigned short As[128][32];
  __shared__ unsigned short Bs[128][32];
  const int t = threadIdx.x;
  const int lane = t & 63, wave = t >> 6;
  const int wm = wave >> 1, wn = wave & 1;
  const int quad = lane >> 4, lo = lane & 15;
  const int m0 = blockIdx.x * 128, n0 = blockIdx.y * 128;   // m = h, n = b
  const int split = blockIdx.z;
  const int kbeg = split * CHUNK;
  const int kend = (kbeg + CHUNK < VPAD) ? kbeg + CHUNK : VPAD;
  const int ar = t >> 2, ac = (t & 3) * 8;
  f32x4 acc[4][4];
  for (int i = 0; i < 4; i++)
    for (int j = 0; j < 4; j++) acc[i][j] = (f32x4){0.f, 0.f, 0.f, 0.f};
  const unsigned short* aptr  = &A[(size_t)(m0 + ar) * VPAD + ac];
  const unsigned short* aptr2 = &A[(size_t)(m0 + ar + 64) * VPAD + ac];
  const unsigned short* bptr  = &Bm[(size_t)(n0 + ar) * VPAD + ac];
  const unsigned short* bptr2 = &Bm[(size_t)(n0 + ar + 64) * VPAD + ac];
  for (int k0 = kbeg; k0 < kend; k0 += 32) {
    uint4 av0 = *(const uint4*)(aptr + k0);
    uint4 av1 = *(const uint4*)(aptr2 + k0);
    uint4 bv0 = *(const uint4*)(bptr + k0);
    uint4 bv1 = *(const uint4*)(bptr2 + k0);
    __syncthreads();
    *(uint4*)&As[ar][ac]      = av0;
    *(uint4*)&As[ar + 64][ac] = av1;
    *(uint4*)&Bs[ar][ac]      = bv0;
    *(uint4*)&Bs[ar + 64][ac] = bv1;
    __syncthreads();
    bf16x8 af[4], bfr[4];
    for (int i = 0; i < 4; i++) {
      af[i]  = *(const bf16x8*)&As[wm * 64 + i * 16 + lo][quad * 8];
      bfr[i] = *(const bf16x8*)&Bs[wn * 64 + i * 16 + lo][quad * 8];
    }
    for (int mi = 0; mi < 4; mi++)
      for (int ni = 0; ni < 4; ni++)
        acc[mi][ni] = __builtin_amdgcn_mfma_f32_16x16x32_bf16(af[mi], bfr[ni], acc[mi][ni], 0, 0, 0);
  }
  float* outp = Pp + (size_t)split * HID * BATCH;
  for (int mi = 0; mi < 4; mi++)
    for (int ni = 0; ni < 4; ni++)
      for (int r = 0; r < 4; r++) {
        int h = m0 + wm * 64 + mi * 16 + quad * 4 + r;
        int b = n0 + wn * 64 + ni * 16 + lo;
        outp[h * BATCH + b] = acc[mi][ni][r];
      }
}

// out[b][h] = (sum_s Pp[s][h][b]) / l[b]
__global__ __launch_bounds__(256) void k_reduce(const float* __restrict__ Pp,
                                                const float* __restrict__ l,
                                                float* __restrict__ out) {
  int idx = blockIdx.x * 256 + threadIdx.x;   // h*256 + b
  int h = idx >> 8, b = idx & 255;
  float s = 0.f;
  for (int i = 0; i < SPLITS; i++) s += Pp[(size_t)i * (HID * BATCH) + idx];
  out[b * HID + h] = s / l[b];
}

// ---------------- launch ----------------

extern "C" void kernel_launch(void* const* d_in, const int* in_sizes, int n_in,
                              void* d_out, int out_size, void* d_ws, size_t ws_size,
                              hipStream_t stream) {
  const float* obs  = (const float*)d_in[0];   // [256,3,84,84]
  const float* W    = (const float*)d_in[1];   // [50257,768]
  const float* proj = (const float*)d_in[2];   // [768,7056]
  const int* beta   = (const int*)d_in[3];     // scalar int
  float* out = (float*)d_out;                  // [256,768] f32

  char* ws = (char*)d_ws;
  size_t off = 0;
  auto alloc = [&](size_t bytes) -> void* {
    void* p = ws + off;
    off = (off + bytes + 255) & ~(size_t)255;
    return p;
  };
  unsigned short* Wb    = (unsigned short*)alloc((size_t)VPAD * HID * 2);   // 77.3 MB
  unsigned short* WbT   = (unsigned short*)alloc((size_t)HID * VPAD * 2);   // 77.3 MB
  float* inv_en         = (float*)alloc((size_t)VPAD * 4);
  unsigned short* obsb  = (unsigned short*)alloc((size_t)BATCH * INPAD * 2);
  unsigned short* projb = (unsigned short*)alloc((size_t)HID * INPAD * 2);
  float* q              = (float*)alloc((size_t)BATCH * HID * 4);
  unsigned short* qhat  = (unsigned short*)alloc((size_t)BATCH * HID * 2);
  float* l              = (float*)alloc((size_t)BATCH * 4);
  unsigned short* E     = (unsigned short*)alloc((size_t)BATCH * VPAD * 2);  // 25.8 MB
  float* Pp             = (float*)alloc((size_t)SPLITS * BATCH * HID * 4);   // 25.2 MB
  (void)ws_size; (void)in_sizes; (void)n_in; (void)out_size;                 // ~221 MB total

  k_wb   <<<dim3(VPAD), dim3(256), 0, stream>>>(W, Wb, inv_en);
  k_wbt  <<<dim3(VPAD / 64, HID / 64), dim3(64, 4), 0, stream>>>(W, WbT);
  k_obs  <<<dim3(BATCH), dim3(256), 0, stream>>>(obs, obsb);
  k_proj <<<dim3(HID), dim3(256), 0, stream>>>(proj, projb);
  k_qgemm<<<dim3(HID / 64, BATCH / 64), dim3(256), 0, stream>>>(obsb, projb, q);
  k_qhat <<<dim3(BATCH), dim3(256), 0, stream>>>(q, beta, qhat, l);
  k_gemm1<<<dim3(VPAD / 128, BATCH / 128), dim3(256), 0, stream>>>(qhat, Wb, inv_en, E, l);
  k_gemm2<<<dim3(HID / 128, BATCH / 128, SPLITS), dim3(256), 0, stream>>>(WbT, E, Pp);
  k_reduce<<<dim3(BATCH * HID / 256), dim3(256), 0, stream>>>(Pp, l, out);
}

// Round 4
// 567.228 us; speedup vs baseline: 1.3957x; 1.3957x over previous
//
#include <hip/hip_runtime.h>

// FrozenHopfield: obs-mean -> random projection -> cosine-sim attention over
// vocab embeddings -> softmax(beta*sims) @ word_embs.
//
// B=256, C=3, HW=7056, HID=768, VOCAB=50257. Two big GEMMs in bf16 MFMA
// 16x16x32, fp32 accumulate. Logits bounded in [-8,8] so softmax needs no
// max subtraction: E=exp(logit), state=(E@W)/rowsum(E).
//
// R2 lesson (rocprof): scattered global_store_short epilogue -> ~37x HBM write
// amplification (975 MB vs 25.8 MB payload). All bf16 stores packed >=4B/lane;
// gemm1 stages its E tile in LDS and writes full 256B rows.
// R3 lesson: k_wbt's store phase only covered 16 of 32 v-pairs per tile ->
// half of WbT was 0xAA poison. Store phase now r=t>>5, j=t&31, 8 passes.

#define VOCAB 50257
#define VPAD  50304   // 393*128
#define HID   768
#define BATCH 256
#define IN    7056
#define INPAD 7072    // 221*32
#define NPAIR (INPAD / 2)   // 3536
#define SPLITS 32
#define CHUNK 1600    // k-elems per split (1600*32 = 51200 >= VPAD)

typedef __attribute__((ext_vector_type(8))) __bf16 bf16x8;
typedef __attribute__((ext_vector_type(4))) float f32x4;

__device__ inline unsigned short f2bf(float f) {
  union { float f; unsigned u; } v; v.f = f;
  unsigned r = v.u + 0x7fffu + ((v.u >> 16) & 1u);   // RNE
  return (unsigned short)(r >> 16);
}
__device__ inline unsigned pack2(float lo, float hi) {
  return (unsigned)f2bf(lo) | ((unsigned)f2bf(hi) << 16);
}

// ---------------- prep kernels ----------------

// Wb[v][h] = bf16(W[v][h]) (zero pad rows), inv_en[v] = 1/||W_v|| (0 for pads)
// 128 threads, 3 col-pairs each (384 pairs = 768 cols), packed uint stores.
__global__ __launch_bounds__(128) void k_wb(const float* __restrict__ W,
                                            unsigned* __restrict__ Wb,   // as uint pairs
                                            float* __restrict__ inv_en) {
  int v = blockIdx.x, t = threadIdx.x;
  float ss = 0.f;
  if (v < VOCAB) {
    for (int i = 0; i < 3; i++) {
      int p = t + i * 128;
      float2 xy = *(const float2*)&W[(size_t)v * HID + 2 * p];
      Wb[(size_t)v * (HID / 2) + p] = pack2(xy.x, xy.y);
      ss += xy.x * xy.x + xy.y * xy.y;
    }
  } else {
    for (int i = 0; i < 3; i++) Wb[(size_t)v * (HID / 2) + t + i * 128] = 0u;
  }
  for (int m = 1; m < 64; m <<= 1) ss += __shfl_xor(ss, m, 64);
  __shared__ float sacc[2];
  if ((t & 63) == 0) sacc[t >> 6] = ss;
  __syncthreads();
  if (t == 0) {
    float tot = sacc[0] + sacc[1];
    inv_en[v] = (v < VOCAB) ? (1.f / sqrtf(tot)) : 0.f;
  }
}

// WbT[h][v] = bf16(W[v][h]) via 64x64 LDS tile transpose; packed uint stores.
__global__ __launch_bounds__(256) void k_wbt(const float* __restrict__ W,
                                             unsigned* __restrict__ WbT) {  // as uint pairs
  __shared__ float Ts[64][65];
  int v0 = blockIdx.x * 64, h0 = blockIdx.y * 64;
  const int t = threadIdx.x;
  // load: 16 lanes per v-row (float4), 16 rows per pass, 4 passes
  {
    int r = t >> 4, c4 = (t & 15) * 4;
    for (int i = 0; i < 4; i++) {
      int v = v0 + r + i * 16;
      float4 x = (v < VOCAB) ? *(const float4*)&W[(size_t)v * HID + h0 + c4]
                             : (float4){0.f, 0.f, 0.f, 0.f};
      Ts[r + i * 16][c4] = x.x; Ts[r + i * 16][c4 + 1] = x.y;
      Ts[r + i * 16][c4 + 2] = x.z; Ts[r + i * 16][c4 + 3] = x.w;
    }
  }
  __syncthreads();
  // store: h-row hr, v-pair j (32 pairs = 64 v-cols); 8 rows/pass, 8 passes
  {
    int r = t >> 5, j = t & 31;
    for (int i = 0; i < 8; i++) {
      int hr = r + i * 8;
      WbT[(size_t)(h0 + hr) * (VPAD / 2) + (v0 >> 1) + j] = pack2(Ts[2 * j][hr], Ts[2 * j + 1][hr]);
    }
  }
}

// obsb[b][i] = bf16(mean_c obs[b][c][i]), zero pad cols; packed uint stores
__global__ __launch_bounds__(256) void k_obs(const float* __restrict__ obs,
                                             unsigned* __restrict__ obsb) {
  int b = blockIdx.x, t = threadIdx.x;
  const size_t base = (size_t)b * 3 * IN;
  for (int p = t; p < NPAIR; p += 256) {
    float x = 0.f, y = 0.f;
    if (2 * p < IN) {   // IN even: pair never straddles the boundary
      float2 a0 = *(const float2*)&obs[base + 2 * p];
      float2 a1 = *(const float2*)&obs[base + IN + 2 * p];
      float2 a2 = *(const float2*)&obs[base + 2 * IN + 2 * p];
      x = (a0.x + a1.x + a2.x) * (1.f / 3.f);
      y = (a0.y + a1.y + a2.y) * (1.f / 3.f);
    }
    obsb[b * NPAIR + p] = pack2(x, y);
  }
}

__global__ __launch_bounds__(256) void k_proj(const float* __restrict__ proj,
                                              unsigned* __restrict__ projb) {
  int h = blockIdx.x, t = threadIdx.x;
  for (int p = t; p < NPAIR; p += 256) {
    float x = 0.f, y = 0.f;
    if (2 * p < IN) {
      float2 xy = *(const float2*)&proj[(size_t)h * IN + 2 * p];
      x = xy.x; y = xy.y;
    }
    projb[h * NPAIR + p] = pack2(x, y);
  }
}

// ---------------- q projection GEMM: q = obs @ proj^T  (64x64 tile, BK=32) ----

__global__ __launch_bounds__(256) void k_qgemm(const unsigned short* __restrict__ A,  // obsb [256][INPAD]
                                               const unsigned short* __restrict__ Bm, // projb [768][INPAD]
                                               float* __restrict__ q) {
  __shared__ unsigned short As[64][32];
  __shared__ unsigned short Bs[64][32];
  const int t = threadIdx.x;
  const int lane = t & 63, wave = t >> 6;
  const int wm = wave >> 1, wn = wave & 1;
  const int quad = lane >> 4, lo = lane & 15;
  const int m0 = blockIdx.y * 64, n0 = blockIdx.x * 64;
  const int ar = t >> 2, ac = (t & 3) * 8;
  f32x4 acc[2][2];
  for (int i = 0; i < 2; i++)
    for (int j = 0; j < 2; j++) acc[i][j] = (f32x4){0.f, 0.f, 0.f, 0.f};
  const unsigned short* aptr = &A[(m0 + ar) * INPAD + ac];
  const unsigned short* bptr = &Bm[(n0 + ar) * INPAD + ac];
  for (int k0 = 0; k0 < INPAD; k0 += 32) {
    uint4 av = *(const uint4*)(aptr + k0);
    uint4 bv = *(const uint4*)(bptr + k0);
    __syncthreads();
    *(uint4*)&As[ar][ac] = av;
    *(uint4*)&Bs[ar][ac] = bv;
    __syncthreads();
    bf16x8 af[2], bfr[2];
    for (int i = 0; i < 2; i++) {
      af[i]  = *(const bf16x8*)&As[wm * 32 + i * 16 + lo][quad * 8];
      bfr[i] = *(const bf16x8*)&Bs[wn * 32 + i * 16 + lo][quad * 8];
    }
    for (int mi = 0; mi < 2; mi++)
      for (int ni = 0; ni < 2; ni++)
        acc[mi][ni] = __builtin_amdgcn_mfma_f32_16x16x32_bf16(af[mi], bfr[ni], acc[mi][ni], 0, 0, 0);
  }
  for (int mi = 0; mi < 2; mi++)
    for (int ni = 0; ni < 2; ni++)
      for (int r = 0; r < 4; r++) {
        int row = m0 + wm * 32 + mi * 16 + quad * 4 + r;   // b
        int col = n0 + wn * 32 + ni * 16 + lo;             // h
        q[row * HID + col] = acc[mi][ni][r];               // 4B/lane, 16-lane contig
      }
}

// qhat[b][h] = bf16(q * beta/||q_b||); packed uint stores; zero l
__global__ __launch_bounds__(384) void k_qhat(const float* __restrict__ q,
                                              const int* __restrict__ beta,
                                              unsigned* __restrict__ qhat,
                                              float* __restrict__ l) {
  int b = blockIdx.x, t = threadIdx.x;   // 384 threads: pair t = cols 2t,2t+1
  float2 xy = *(const float2*)&q[b * HID + 2 * t];
  float ss = xy.x * xy.x + xy.y * xy.y;
  for (int m = 1; m < 64; m <<= 1) ss += __shfl_xor(ss, m, 64);
  __shared__ float sacc[6];
  if ((t & 63) == 0) sacc[t >> 6] = ss;
  __syncthreads();
  float tot = sacc[0] + sacc[1] + sacc[2] + sacc[3] + sacc[4] + sacc[5];
  // ref denom is (qn*en + 1e-8); qn*en ~ 1.3e3 so eps is rel ~7e-12: folded out.
  float scale = (float)beta[0] / sqrtf(tot);
  qhat[b * (HID / 2) + t] = pack2(xy.x * scale, xy.y * scale);
  if (t == 0) l[b] = 0.f;
}

// ---------------- GEMM1: E = exp((qhat @ Wb^T) * inv_en), rowsums into l ----
// grid (2 m-blocks, 393 n-blocks): adjacent blocks share the Wb stripe -> L2 hit.

__global__ __launch_bounds__(256) void k_gemm1(const unsigned short* __restrict__ A,   // qhat [256][768]
                                               const unsigned short* __restrict__ Bm,  // Wb [VPAD][768]
                                               const float* __restrict__ inv_en,
                                               unsigned short* __restrict__ E,         // [256][VPAD]
                                               float* __restrict__ l) {
  __shared__ unsigned short As[128][32];
  __shared__ unsigned short Bs[128][32];
  __shared__ unsigned short Et[128][128];   // staged output tile (32 KB)
  __shared__ float rowsum[128];
  const int t = threadIdx.x;
  const int lane = t & 63, wave = t >> 6;
  const int wm = wave >> 1, wn = wave & 1;
  const int quad = lane >> 4, lo = lane & 15;
  const int m0 = blockIdx.x * 128, n0 = blockIdx.y * 128;
  const int ar = t >> 2, ac = (t & 3) * 8;
  if (t < 128) rowsum[t] = 0.f;
  f32x4 acc[4][4];
  for (int i = 0; i < 4; i++)
    for (int j = 0; j < 4; j++) acc[i][j] = (f32x4){0.f, 0.f, 0.f, 0.f};
  const unsigned short* aptr  = &A[(m0 + ar) * HID + ac];
  const unsigned short* aptr2 = &A[(m0 + ar + 64) * HID + ac];
  const unsigned short* bptr  = &Bm[(size_t)(n0 + ar) * HID + ac];
  const unsigned short* bptr2 = &Bm[(size_t)(n0 + ar + 64) * HID + ac];
  for (int k0 = 0; k0 < HID; k0 += 32) {
    uint4 av0 = *(const uint4*)(aptr + k0);
    uint4 av1 = *(const uint4*)(aptr2 + k0);
    uint4 bv0 = *(const uint4*)(bptr + k0);
    uint4 bv1 = *(const uint4*)(bptr2 + k0);
    __syncthreads();
    *(uint4*)&As[ar][ac]      = av0;
    *(uint4*)&As[ar + 64][ac] = av1;
    *(uint4*)&Bs[ar][ac]      = bv0;
    *(uint4*)&Bs[ar + 64][ac] = bv1;
    __syncthreads();
    bf16x8 af[4], bfr[4];
    for (int i = 0; i < 4; i++) {
      af[i]  = *(const bf16x8*)&As[wm * 64 + i * 16 + lo][quad * 8];
      bfr[i] = *(const bf16x8*)&Bs[wn * 64 + i * 16 + lo][quad * 8];
    }
    for (int mi = 0; mi < 4; mi++)
      for (int ni = 0; ni < 4; ni++)
        acc[mi][ni] = __builtin_amdgcn_mfma_f32_16x16x32_bf16(af[mi], bfr[ni], acc[mi][ni], 0, 0, 0);
  }
  // epilogue: E = exp(acc * inv_en) into LDS tile + rowsum reduce
  for (int mi = 0; mi < 4; mi++)
    for (int ni = 0; ni < 4; ni++) {
      int cl = wn * 64 + ni * 16 + lo;
      int vg = n0 + cl;
      float ie = inv_en[vg];
      bool valid = (vg < VOCAB);
      for (int r = 0; r < 4; r++) {
        int row = wm * 64 + mi * 16 + quad * 4 + r;
        float e = valid ? __expf(acc[mi][ni][r] * ie) : 0.f;   // logits in [-8,8]
        Et[row][cl] = f2bf(e);
        float s = e;
        s += __shfl_xor(s, 1, 64);
        s += __shfl_xor(s, 2, 64);
        s += __shfl_xor(s, 4, 64);
        s += __shfl_xor(s, 8, 64);
        if (lo == 0) atomicAdd(&rowsum[row], s);
      }
    }
  __syncthreads();
  // cooperative full-line writes: 128 rows x 256B, uint4 (16B/lane)
  for (int i = 0; i < 8; i++) {
    int idx = t + i * 256;
    int row = idx >> 4, j = idx & 15;
    *(uint4*)&E[(size_t)(m0 + row) * VPAD + n0 + j * 8] = *(const uint4*)&Et[row][j * 8];
  }
  if (t < 128) atomicAdd(&l[m0 + t], rowsum[t]);
}

// ---------------- GEMM2 (K-split): Pp[s][h][b] = partial sum_v WbT[h][v]*E[b][v] ----

__global__ __launch_bounds__(256) void k_gemm2(const unsigned short* __restrict__ A,   // WbT [768][VPAD]
                                               const unsigned short* __restrict__ Bm,  // E [256][VPAD]
                                               float* __restrict__ Pp) {
  __shared__ unsigned short As[128][32];
  __shared__ unsigned short Bs[128][32];
  const int t = threadIdx.x;
  const int lane = t & 63, wave = t >> 6;
  const int wm = wave >> 1, wn = wave & 1;
  const int quad = lane >> 4, lo = lane & 15;
  const int m0 = blockIdx.x * 128, n0 = blockIdx.y * 128;   // m = h, n = b
  const int split = blockIdx.z;
  const int kbeg = split * CHUNK;
  const int kend = (kbeg + CHUNK < VPAD) ? kbeg + CHUNK : VPAD;
  const int ar = t >> 2, ac = (t & 3) * 8;
  f32x4 acc[4][4];
  for (int i = 0; i < 4; i++)
    for (int j = 0; j < 4; j++) acc[i][j] = (f32x4){0.f, 0.f, 0.f, 0.f};
  const unsigned short* aptr  = &A[(size_t)(m0 + ar) * VPAD + ac];
  const unsigned short* aptr2 = &A[(size_t)(m0 + ar + 64) * VPAD + ac];
  const unsigned short* bptr  = &Bm[(size_t)(n0 + ar) * VPAD + ac];
  const unsigned short* bptr2 = &Bm[(size_t)(n0 + ar + 64) * VPAD + ac];
  for (int k0 = kbeg; k0 < kend; k0 += 32) {
    uint4 av0 = *(const uint4*)(aptr + k0);
    uint4 av1 = *(const uint4*)(aptr2 + k0);
    uint4 bv0 = *(const uint4*)(bptr + k0);
    uint4 bv1 = *(const uint4*)(bptr2 + k0);
    __syncthreads();
    *(uint4*)&As[ar][ac]      = av0;
    *(uint4*)&As[ar + 64][ac] = av1;
    *(uint4*)&Bs[ar][ac]      = bv0;
    *(uint4*)&Bs[ar + 64][ac] = bv1;
    __syncthreads();
    bf16x8 af[4], bfr[4];
    for (int i = 0; i < 4; i++) {
      af[i]  = *(const bf16x8*)&As[wm * 64 + i * 16 + lo][quad * 8];
      bfr[i] = *(const bf16x8*)&Bs[wn * 64 + i * 16 + lo][quad * 8];
    }
    for (int mi = 0; mi < 4; mi++)
      for (int ni = 0; ni < 4; ni++)
        acc[mi][ni] = __builtin_amdgcn_mfma_f32_16x16x32_bf16(af[mi], bfr[ni], acc[mi][ni], 0, 0, 0);
  }
  float* outp = Pp + (size_t)split * HID * BATCH;
  for (int mi = 0; mi < 4; mi++)
    for (int ni = 0; ni < 4; ni++)
      for (int r = 0; r < 4; r++) {
        int h = m0 + wm * 64 + mi * 16 + quad * 4 + r;
        int b = n0 + wn * 64 + ni * 16 + lo;
        outp[h * BATCH + b] = acc[mi][ni][r];   // 4B/lane, 16-lane contig
      }
}

// out[b][h] = (sum_s Pp[s][h][b]) / l[b]
__global__ __launch_bounds__(256) void k_reduce(const float* __restrict__ Pp,
                                                const float* __restrict__ l,
                                                float* __restrict__ out) {
  int idx = blockIdx.x * 256 + threadIdx.x;   // h*256 + b
  int h = idx >> 8, b = idx & 255;
  float s = 0.f;
  for (int i = 0; i < SPLITS; i++) s += Pp[(size_t)i * (HID * BATCH) + idx];
  out[b * HID + h] = s / l[b];
}

// ---------------- launch ----------------

extern "C" void kernel_launch(void* const* d_in, const int* in_sizes, int n_in,
                              void* d_out, int out_size, void* d_ws, size_t ws_size,
                              hipStream_t stream) {
  const float* obs  = (const float*)d_in[0];   // [256,3,84,84]
  const float* W    = (const float*)d_in[1];   // [50257,768]
  const float* proj = (const float*)d_in[2];   // [768,7056]
  const int* beta   = (const int*)d_in[3];     // scalar int
  float* out = (float*)d_out;                  // [256,768] f32

  char* ws = (char*)d_ws;
  size_t off = 0;
  auto alloc = [&](size_t bytes) -> void* {
    void* p = ws + off;
    off = (off + bytes + 255) & ~(size_t)255;
    return p;
  };
  unsigned short* Wb    = (unsigned short*)alloc((size_t)VPAD * HID * 2);   // 77.3 MB
  unsigned short* WbT   = (unsigned short*)alloc((size_t)HID * VPAD * 2);   // 77.3 MB
  float* inv_en         = (float*)alloc((size_t)VPAD * 4);
  unsigned short* obsb  = (unsigned short*)alloc((size_t)BATCH * INPAD * 2);
  unsigned short* projb = (unsigned short*)alloc((size_t)HID * INPAD * 2);
  float* q              = (float*)alloc((size_t)BATCH * HID * 4);
  unsigned short* qhat  = (unsigned short*)alloc((size_t)BATCH * HID * 2);
  float* l              = (float*)alloc((size_t)BATCH * 4);
  unsigned short* E     = (unsigned short*)alloc((size_t)BATCH * VPAD * 2);  // 25.8 MB
  float* Pp             = (float*)alloc((size_t)SPLITS * BATCH * HID * 4);   // 25.2 MB
  (void)ws_size; (void)in_sizes; (void)n_in; (void)out_size;                 // ~221 MB total

  k_wb   <<<dim3(VPAD), dim3(128), 0, stream>>>(W, (unsigned*)Wb, inv_en);
  k_wbt  <<<dim3(VPAD / 64, HID / 64), dim3(256), 0, stream>>>(W, (unsigned*)WbT);
  k_obs  <<<dim3(BATCH), dim3(256), 0, stream>>>(obs, (unsigned*)obsb);
  k_proj <<<dim3(HID), dim3(256), 0, stream>>>(proj, (unsigned*)projb);
  k_qgemm<<<dim3(HID / 64, BATCH / 64), dim3(256), 0, stream>>>(obsb, projb, q);
  k_qhat <<<dim3(BATCH), dim3(384), 0, stream>>>(q, beta, (unsigned*)qhat, l);
  k_gemm1<<<dim3(BATCH / 128, VPAD / 128), dim3(256), 0, stream>>>(qhat, Wb, inv_en, E, l);
  k_gemm2<<<dim3(HID / 128, BATCH / 128, SPLITS), dim3(256), 0, stream>>>(WbT, E, Pp);
  k_reduce<<<dim3(BATCH * HID / 256), dim3(256), 0, stream>>>(Pp, l, out);
}

// Round 5
// 457.835 us; speedup vs baseline: 1.7291x; 1.2389x over previous
//
#include <hip/hip_runtime.h>

// FrozenHopfield: obs-mean -> random projection -> cosine-sim attention over
// vocab embeddings -> softmax(beta*sims) @ word_embs.
//
// B=256, C=3, HW=7056, HID=768, VOCAB=50257. Two big GEMMs in bf16 MFMA
// 16x16x32, fp32 accumulate. Logits bounded in [-8,8] so softmax needs no
// max subtraction: E=exp(logit), state=(E@W)/rowsum(E).
//
// R2 lesson (rocprof): scattered global_store_short epilogue -> ~37x HBM write
// amplification. All bf16 stores packed >=4B/lane; gemm1 stages its E tile in
// LDS and writes full 256B rows.
// R3 lesson: partial-coverage LDS store phases are silent poison. Every
// cooperative loop's coverage is now annotated with its element count.
// R4 lesson (rocprof): k_qgemm at 48 blocks was latency-bound (Occupancy 2.1%,
// 115 us). Now K-split 17 ways (816 blocks) with fp32 partials summed in
// k_qhat. k_wb+k_wbt fused into k_wprep: W (154 MB) read once, not twice.

#define VOCAB 50257
#define VPAD  50304   // 393*128
#define HID   768
#define BATCH 256
#define IN    7056
#define INPAD 7072    // 221*32 = 17*416
#define NPAIR (INPAD / 2)   // 3536
#define SPLITS 32
#define CHUNK 1600    // gemm2 k-elems per split (1600*32 = 51200 >= VPAD)
#define QSPLITS 17
#define QCHUNK 416    // 13 iters of 32

typedef __attribute__((ext_vector_type(8))) __bf16 bf16x8;
typedef __attribute__((ext_vector_type(4))) float f32x4;

__device__ inline unsigned short f2bf(float f) {
  union { float f; unsigned u; } v; v.f = f;
  unsigned r = v.u + 0x7fffu + ((v.u >> 16) & 1u);   // RNE
  return (unsigned short)(r >> 16);
}
__device__ inline unsigned pack2(float lo, float hi) {
  return (unsigned)f2bf(lo) | ((unsigned)f2bf(hi) << 16);
}

// ---------------- W prep (fused): Wb, WbT, inv_en in one pass over W ----------
// Block: 32 v-rows x 768 h. LDS bf16 tile 32x776 (pad 8 breaks phase-2b
// power-of-2 striding; row pitch 1552B stays 16B-aligned for uint4 reads).
__global__ __launch_bounds__(256) void k_wprep(const float* __restrict__ W,
                                               unsigned* __restrict__ Wb,    // [VPAD][384] uint pairs
                                               unsigned* __restrict__ WbT,   // [768][VPAD/2] uint pairs
                                               float* __restrict__ inv_en) {
  __shared__ unsigned short Sb[32][776];
  const int t = threadIdx.x;
  const int v0 = blockIdx.x * 32;
  // phase 1: row r = t>>3 (8 lanes/row), lane c8 = t&7 covers cols [c8*96, +96)
  const int r = t >> 3, c8 = t & 7;
  const int v = v0 + r;
  float ss = 0.f;
  if (v < VOCAB) {
    const float* wrow = &W[(size_t)v * HID + c8 * 96];
    for (int i = 0; i < 24; i++) {                      // 24 float4 = 96 cols
      float4 x = *(const float4*)(wrow + i * 4);
      int c = c8 * 96 + i * 4;
      Sb[r][c] = f2bf(x.x); Sb[r][c + 1] = f2bf(x.y);
      Sb[r][c + 2] = f2bf(x.z); Sb[r][c + 3] = f2bf(x.w);
      ss += x.x * x.x + x.y * x.y + x.z * x.z + x.w * x.w;
    }
  } else {
    for (int i = 0; i < 24; i++) {
      int c = c8 * 96 + i * 4;
      *(uint2*)&Sb[r][c] = (uint2){0u, 0u};             // 4 ushorts
    }
  }
  // row-norm: reduce the 8 lanes of this row (xor of low 3 bits keeps t>>3)
  ss += __shfl_xor(ss, 1, 64);
  ss += __shfl_xor(ss, 2, 64);
  ss += __shfl_xor(ss, 4, 64);
  if (c8 == 0) inv_en[v] = (v < VOCAB) ? (1.f / sqrtf(ss)) : 0.f;
  __syncthreads();
  // phase 2a: Wb rows. 32*384 = 12288 uints; 12 passes x 256 thr x uint4
  // lane-contiguous: pass i writes uints [i*4096, +4096).
  for (int i = 0; i < 12; i++) {
    int f = (i * 256 + t) * 4;                // uint index, 4-aligned
    int row = f / 384, cp = f % 384;          // cp multiple of 4 -> 16B aligned
    *(uint4*)&Wb[(size_t)(v0 + row) * 384 + cp] = *(const uint4*)&Sb[row][2 * cp];
  }
  // phase 2b: WbT. Each h-row hr gets v-locals 0..31 (16 uints = 64B):
  // 4 lanes/row x 64 rows/pass x 12 passes = 768 rows. Full coverage.
  for (int p = 0; p < 12; p++) {
    int hr = p * 64 + (t >> 2), li = t & 3;
    unsigned u[4];
    for (int j = 0; j < 4; j++) {
      int vl = li * 8 + j * 2;
      u[j] = (unsigned)Sb[vl][hr] | ((unsigned)Sb[vl + 1][hr] << 16);
    }
    *(uint4*)&WbT[(size_t)hr * (VPAD / 2) + (v0 >> 1) + li * 4] = *(const uint4*)u;
  }
}

// obsb[b][i] = bf16(mean_c obs[b][c][i]), zero pad cols; packed uint stores
__global__ __launch_bounds__(256) void k_obs(const float* __restrict__ obs,
                                             unsigned* __restrict__ obsb) {
  int b = blockIdx.x, t = threadIdx.x;
  const size_t base = (size_t)b * 3 * IN;
  for (int p = t; p < NPAIR; p += 256) {
    float x = 0.f, y = 0.f;
    if (2 * p < IN) {   // IN even: pair never straddles the boundary
      float2 a0 = *(const float2*)&obs[base + 2 * p];
      float2 a1 = *(const float2*)&obs[base + IN + 2 * p];
      float2 a2 = *(const float2*)&obs[base + 2 * IN + 2 * p];
      x = (a0.x + a1.x + a2.x) * (1.f / 3.f);
      y = (a0.y + a1.y + a2.y) * (1.f / 3.f);
    }
    obsb[b * NPAIR + p] = pack2(x, y);
  }
}

__global__ __launch_bounds__(256) void k_proj(const float* __restrict__ proj,
                                              unsigned* __restrict__ projb) {
  int h = blockIdx.x, t = threadIdx.x;
  for (int p = t; p < NPAIR; p += 256) {
    float x = 0.f, y = 0.f;
    if (2 * p < IN) {
      float2 xy = *(const float2*)&proj[(size_t)h * IN + 2 * p];
      x = xy.x; y = xy.y;
    }
    projb[h * NPAIR + p] = pack2(x, y);
  }
}

// ---------------- q projection GEMM (K-split): qp[s] = partial obs @ proj^T ----

__global__ __launch_bounds__(256) void k_qgemm(const unsigned short* __restrict__ A,  // obsb [256][INPAD]
                                               const unsigned short* __restrict__ Bm, // projb [768][INPAD]
                                               float* __restrict__ qp) {              // [QSPLITS][256][768]
  __shared__ unsigned short As[64][32];
  __shared__ unsigned short Bs[64][32];
  const int t = threadIdx.x;
  const int lane = t & 63, wave = t >> 6;
  const int wm = wave >> 1, wn = wave & 1;
  const int quad = lane >> 4, lo = lane & 15;
  const int m0 = blockIdx.y * 64, n0 = blockIdx.x * 64;
  const int split = blockIdx.z;
  const int kbeg = split * QCHUNK, kend = kbeg + QCHUNK;
  const int ar = t >> 2, ac = (t & 3) * 8;
  f32x4 acc[2][2];
  for (int i = 0; i < 2; i++)
    for (int j = 0; j < 2; j++) acc[i][j] = (f32x4){0.f, 0.f, 0.f, 0.f};
  const unsigned short* aptr = &A[(m0 + ar) * INPAD + ac];
  const unsigned short* bptr = &Bm[(n0 + ar) * INPAD + ac];
  for (int k0 = kbeg; k0 < kend; k0 += 32) {
    uint4 av = *(const uint4*)(aptr + k0);
    uint4 bv = *(const uint4*)(bptr + k0);
    __syncthreads();
    *(uint4*)&As[ar][ac] = av;
    *(uint4*)&Bs[ar][ac] = bv;
    __syncthreads();
    bf16x8 af[2], bfr[2];
    for (int i = 0; i < 2; i++) {
      af[i]  = *(const bf16x8*)&As[wm * 32 + i * 16 + lo][quad * 8];
      bfr[i] = *(const bf16x8*)&Bs[wn * 32 + i * 16 + lo][quad * 8];
    }
    for (int mi = 0; mi < 2; mi++)
      for (int ni = 0; ni < 2; ni++)
        acc[mi][ni] = __builtin_amdgcn_mfma_f32_16x16x32_bf16(af[mi], bfr[ni], acc[mi][ni], 0, 0, 0);
  }
  float* outp = qp + (size_t)split * BATCH * HID;
  for (int mi = 0; mi < 2; mi++)
    for (int ni = 0; ni < 2; ni++)
      for (int r = 0; r < 4; r++) {
        int row = m0 + wm * 32 + mi * 16 + quad * 4 + r;   // b
        int col = n0 + wn * 32 + ni * 16 + lo;             // h
        outp[row * HID + col] = acc[mi][ni][r];            // 4B/lane, 16-lane contig
      }
}

// qhat[b][h] = bf16(sum_s qp * beta/||q_b||); packed uint stores; zero l
__global__ __launch_bounds__(384) void k_qhat(const float* __restrict__ qp,
                                              const int* __restrict__ beta,
                                              unsigned* __restrict__ qhat,
                                              float* __restrict__ l) {
  int b = blockIdx.x, t = threadIdx.x;   // 384 threads: pair t = cols 2t,2t+1
  float x = 0.f, y = 0.f;
  for (int s = 0; s < QSPLITS; s++) {
    float2 p = *(const float2*)&qp[(size_t)s * BATCH * HID + b * HID + 2 * t];
    x += p.x; y += p.y;
  }
  float ss = x * x + y * y;
  for (int m = 1; m < 64; m <<= 1) ss += __shfl_xor(ss, m, 64);
  __shared__ float sacc[6];
  if ((t & 63) == 0) sacc[t >> 6] = ss;
  __syncthreads();
  float tot = sacc[0] + sacc[1] + sacc[2] + sacc[3] + sacc[4] + sacc[5];
  // ref denom is (qn*en + 1e-8); qn*en ~ 1.3e3 so eps is rel ~7e-12: folded out.
  float scale = (float)beta[0] / sqrtf(tot);
  qhat[b * (HID / 2) + t] = pack2(x * scale, y * scale);
  if (t == 0) l[b] = 0.f;
}

// ---------------- GEMM1: E = exp((qhat @ Wb^T) * inv_en), rowsums into l ----
// grid (2 m-blocks, 393 n-blocks): adjacent blocks share the Wb stripe -> L2 hit.

__global__ __launch_bounds__(256) void k_gemm1(const unsigned short* __restrict__ A,   // qhat [256][768]
                                               const unsigned short* __restrict__ Bm,  // Wb [VPAD][768]
                                               const float* __restrict__ inv_en,
                                               unsigned short* __restrict__ E,         // [256][VPAD]
                                               float* __restrict__ l) {
  __shared__ unsigned short As[128][32];
  __shared__ unsigned short Bs[128][32];
  __shared__ unsigned short Et[128][128];   // staged output tile (32 KB)
  __shared__ float rowsum[128];
  const int t = threadIdx.x;
  const int lane = t & 63, wave = t >> 6;
  const int wm = wave >> 1, wn = wave & 1;
  const int quad = lane >> 4, lo = lane & 15;
  const int m0 = blockIdx.x * 128, n0 = blockIdx.y * 128;
  const int ar = t >> 2, ac = (t & 3) * 8;
  if (t < 128) rowsum[t] = 0.f;
  f32x4 acc[4][4];
  for (int i = 0; i < 4; i++)
    for (int j = 0; j < 4; j++) acc[i][j] = (f32x4){0.f, 0.f, 0.f, 0.f};
  const unsigned short* aptr  = &A[(m0 + ar) * HID + ac];
  const unsigned short* aptr2 = &A[(m0 + ar + 64) * HID + ac];
  const unsigned short* bptr  = &Bm[(size_t)(n0 + ar) * HID + ac];
  const unsigned short* bptr2 = &Bm[(size_t)(n0 + ar + 64) * HID + ac];
  for (int k0 = 0; k0 < HID; k0 += 32) {
    uint4 av0 = *(const uint4*)(aptr + k0);
    uint4 av1 = *(const uint4*)(aptr2 + k0);
    uint4 bv0 = *(const uint4*)(bptr + k0);
    uint4 bv1 = *(const uint4*)(bptr2 + k0);
    __syncthreads();
    *(uint4*)&As[ar][ac]      = av0;
    *(uint4*)&As[ar + 64][ac] = av1;
    *(uint4*)&Bs[ar][ac]      = bv0;
    *(uint4*)&Bs[ar + 64][ac] = bv1;
    __syncthreads();
    bf16x8 af[4], bfr[4];
    for (int i = 0; i < 4; i++) {
      af[i]  = *(const bf16x8*)&As[wm * 64 + i * 16 + lo][quad * 8];
      bfr[i] = *(const bf16x8*)&Bs[wn * 64 + i * 16 + lo][quad * 8];
    }
    for (int mi = 0; mi < 4; mi++)
      for (int ni = 0; ni < 4; ni++)
        acc[mi][ni] = __builtin_amdgcn_mfma_f32_16x16x32_bf16(af[mi], bfr[ni], acc[mi][ni], 0, 0, 0);
  }
  // epilogue: E = exp(acc * inv_en) into LDS tile + rowsum reduce
  for (int mi = 0; mi < 4; mi++)
    for (int ni = 0; ni < 4; ni++) {
      int cl = wn * 64 + ni * 16 + lo;
      int vg = n0 + cl;
      bool valid = (vg < VOCAB);
      float ie = inv_en[vg];
      for (int r = 0; r < 4; r++) {
        int row = wm * 64 + mi * 16 + quad * 4 + r;
        float e = valid ? __expf(acc[mi][ni][r] * ie) : 0.f;   // logits in [-8,8]
        Et[row][cl] = f2bf(e);
        float s = e;
        s += __shfl_xor(s, 1, 64);
        s += __shfl_xor(s, 2, 64);
        s += __shfl_xor(s, 4, 64);
        s += __shfl_xor(s, 8, 64);
        if (lo == 0) atomicAdd(&rowsum[row], s);
      }
    }
  __syncthreads();
  // cooperative full-line writes: 128 rows x 256B: 2048 uint4 = 8 passes x 256
  for (int i = 0; i < 8; i++) {
    int idx = t + i * 256;
    int row = idx >> 4, j = idx & 15;
    *(uint4*)&E[(size_t)(m0 + row) * VPAD + n0 + j * 8] = *(const uint4*)&Et[row][j * 8];
  }
  if (t < 128) atomicAdd(&l[m0 + t], rowsum[t]);
}

// ---------------- GEMM2 (K-split): Pp[s][h][b] = partial sum_v WbT[h][v]*E[b][v] ----

__global__ __launch_bounds__(256) void k_gemm2(const unsigned short* __restrict__ A,   // WbT [768][VPAD]
                                               const unsigned short* __restrict__ Bm,  // E [256][VPAD]
                                               float* __restrict__ Pp) {
  __shared__ unsigned short As[128][32];
  __shared__ unsigned short Bs[128][32];
  const int t = threadIdx.x;
  const int lane = t & 63, wave = t >> 6;
  const int wm = wave >> 1, wn = wave & 1;
  const int quad = lane >> 4, lo = lane & 15;
  const int m0 = blockIdx.x * 128, n0 = blockIdx.y * 128;   // m = h, n = b
  const int split = blockIdx.z;
  const int kbeg = split * CHUNK;
  const int kend = (kbeg + CHUNK < VPAD) ? kbeg + CHUNK : VPAD;
  const int ar = t >> 2, ac = (t & 3) * 8;
  f32x4 acc[4][4];
  for (int i = 0; i < 4; i++)
    for (int j = 0; j < 4; j++) acc[i][j] = (f32x4){0.f, 0.f, 0.f, 0.f};
  const unsigned short* aptr  = &A[(size_t)(m0 + ar) * VPAD + ac];
  const unsigned short* aptr2 = &A[(size_t)(m0 + ar + 64) * VPAD + ac];
  const unsigned short* bptr  = &Bm[(size_t)(n0 + ar) * VPAD + ac];
  const unsigned short* bptr2 = &Bm[(size_t)(n0 + ar + 64) * VPAD + ac];
  for (int k0 = kbeg; k0 < kend; k0 += 32) {
    uint4 av0 = *(const uint4*)(aptr + k0);
    uint4 av1 = *(const uint4*)(aptr2 + k0);
    uint4 bv0 = *(const uint4*)(bptr + k0);
    uint4 bv1 = *(const uint4*)(bptr2 + k0);
    __syncthreads();
    *(uint4*)&As[ar][ac]      = av0;
    *(uint4*)&As[ar + 64][ac] = av1;
    *(uint4*)&Bs[ar][ac]      = bv0;
    *(uint4*)&Bs[ar + 64][ac] = bv1;
    __syncthreads();
    bf16x8 af[4], bfr[4];
    for (int i = 0; i < 4; i++) {
      af[i]  = *(const bf16x8*)&As[wm * 64 + i * 16 + lo][quad * 8];
      bfr[i] = *(const bf16x8*)&Bs[wn * 64 + i * 16 + lo][quad * 8];
    }
    for (int mi = 0; mi < 4; mi++)
      for (int ni = 0; ni < 4; ni++)
        acc[mi][ni] = __builtin_amdgcn_mfma_f32_16x16x32_bf16(af[mi], bfr[ni], acc[mi][ni], 0, 0, 0);
  }
  float* outp = Pp + (size_t)split * HID * BATCH;
  for (int mi = 0; mi < 4; mi++)
    for (int ni = 0; ni < 4; ni++)
      for (int r = 0; r < 4; r++) {
        int h = m0 + wm * 64 + mi * 16 + quad * 4 + r;
        int b = n0 + wn * 64 + ni * 16 + lo;
        outp[h * BATCH + b] = acc[mi][ni][r];   // 4B/lane, 16-lane contig
      }
}

// out[b][h] = (sum_s Pp[s][h][b]) / l[b]
__global__ __launch_bounds__(256) void k_reduce(const float* __restrict__ Pp,
                                                const float* __restrict__ l,
                                                float* __restrict__ out) {
  int idx = blockIdx.x * 256 + threadIdx.x;   // h*256 + b
  int h = idx >> 8, b = idx & 255;
  float s = 0.f;
  for (int i = 0; i < SPLITS; i++) s += Pp[(size_t)i * (HID * BATCH) + idx];
  out[b * HID + h] = s / l[b];
}

// ---------------- launch ----------------

extern "C" void kernel_launch(void* const* d_in, const int* in_sizes, int n_in,
                              void* d_out, int out_size, void* d_ws, size_t ws_size,
                              hipStream_t stream) {
  const float* obs  = (const float*)d_in[0];   // [256,3,84,84]
  const float* W    = (const float*)d_in[1];   // [50257,768]
  const float* proj = (const float*)d_in[2];   // [768,7056]
  const int* beta   = (const int*)d_in[3];     // scalar int
  float* out = (float*)d_out;                  // [256,768] f32

  char* ws = (char*)d_ws;
  size_t off = 0;
  auto alloc = [&](size_t bytes) -> void* {
    void* p = ws + off;
    off = (off + bytes + 255) & ~(size_t)255;
    return p;
  };
  unsigned short* Wb    = (unsigned short*)alloc((size_t)VPAD * HID * 2);   // 77.3 MB
  unsigned short* WbT   = (unsigned short*)alloc((size_t)HID * VPAD * 2);   // 77.3 MB
  float* inv_en         = (float*)alloc((size_t)VPAD * 4);
  unsigned short* obsb  = (unsigned short*)alloc((size_t)BATCH * INPAD * 2);
  unsigned short* projb = (unsigned short*)alloc((size_t)HID * INPAD * 2);
  unsigned short* qhat  = (unsigned short*)alloc((size_t)BATCH * HID * 2);
  float* l              = (float*)alloc((size_t)BATCH * 4);
  unsigned short* E     = (unsigned short*)alloc((size_t)BATCH * VPAD * 2);  // 25.8 MB
  float* Pp             = (float*)alloc((size_t)SPLITS * BATCH * HID * 4);   // 25.2 MB
  float* qp             = Pp;   // alias: qp (13.4 MB) dead before gemm2 writes Pp
  (void)ws_size; (void)in_sizes; (void)n_in; (void)out_size;                 // ~206 MB total

  k_wprep<<<dim3(VPAD / 32), dim3(256), 0, stream>>>(W, (unsigned*)Wb, (unsigned*)WbT, inv_en);
  k_obs  <<<dim3(BATCH), dim3(256), 0, stream>>>(obs, (unsigned*)obsb);
  k_proj <<<dim3(HID), dim3(256), 0, stream>>>(proj, (unsigned*)projb);
  k_qgemm<<<dim3(HID / 64, BATCH / 64, QSPLITS), dim3(256), 0, stream>>>(obsb, projb, qp);
  k_qhat <<<dim3(BATCH), dim3(384), 0, stream>>>(qp, beta, (unsigned*)qhat, l);
  k_gemm1<<<dim3(BATCH / 128, VPAD / 128), dim3(256), 0, stream>>>(qhat, Wb, inv_en, E, l);
  k_gemm2<<<dim3(HID / 128, BATCH / 128, SPLITS), dim3(256), 0, stream>>>(WbT, E, Pp);
  k_reduce<<<dim3(BATCH * HID / 256), dim3(256), 0, stream>>>(Pp, l, out);
}